// Round 23
// baseline (182.440 us; speedup 1.0000x reference)
//
#include <hip/hip_runtime.h>
#include <hip/hip_bf16.h>
#include <cstdint>
#include <cstddef>

#define B_ 2
#define S_ 2048
#define D_ 2048
#define H_ 32
#define KVH_ 8
#define HD_ 64
#define PROJN 3072   // Q_OUT(2048) + 2*KV_OUT(512)

typedef unsigned short u16;
typedef unsigned int u32;
typedef __attribute__((ext_vector_type(8))) short short8;
typedef __attribute__((ext_vector_type(4))) short short4v;
typedef __attribute__((ext_vector_type(4))) float f32x4;

__device__ __forceinline__ u16 f2bf(float f) {
  __hip_bfloat16 h = __float2bfloat16(f);
  return *reinterpret_cast<u16*>(&h);
}

// raw v_exp_f32 (2^x): avoids ocml exp2f libcall expansion (~25 VALU ops)
__device__ __forceinline__ float fast_exp2(float x) {
  float r;
  asm("v_exp_f32 %0, %1" : "=v"(r) : "v"(x));
  return r;
}

// pack two f32 -> two bf16 (round-half-up) in one u32: 2 adds + 1 perm
__device__ __forceinline__ u32 pack2bf(float lo, float hi) {
  u32 a = __float_as_uint(lo) + 0x8000u;
  u32 b = __float_as_uint(hi) + 0x8000u;
  return __builtin_amdgcn_perm(b, a, 0x07060302);  // {b[31:16], a[31:16]}
}

#define GLDS16(g, l)                                                           \
  __builtin_amdgcn_global_load_lds(                                            \
      (const __attribute__((address_space(1))) void*)(g),                      \
      (__attribute__((address_space(3))) void*)(l), 16, 0, 0)

// ---------------- pack f32 -> bf16 (x, w_qkv) + rope tables (one launch) ----
__global__ __launch_bounds__(256) void pack3(const float* __restrict__ x,
                                             const float* __restrict__ wqkv,
                                             u16* __restrict__ xb,
                                             u16* __restrict__ wqkvb,
                                             float* __restrict__ tct,
                                             float* __restrict__ tst) {
  const int bid = blockIdx.x;  // 4096 + 3072 = 7168 pack + 256 tab
  if (bid >= 7168) {
    int i = (bid - 7168) * 256 + threadIdx.x;  // 32*2048
    int j = i >> 11, s = i & 2047;
    float e = (float)(2 * j) / 64.0f;
    float inv_freq = 1.0f / powf(10000.0f, e);
    float ang = (float)s * inv_freq;
    tct[i] = cosf(ang);
    tst[i] = sinf(ang);
    return;
  }
  const float* in;
  u16* out;
  int base;
  if (bid < 4096) { in = x; out = xb; base = bid; }
  else { in = wqkv; out = wqkvb; base = bid - 4096; }
  const int i = (base * 256 + threadIdx.x) * 8;
  const float4* p = reinterpret_cast<const float4*>(in + i);
  float4 a = p[0], b = p[1];
  union { short8 v; u16 u[8]; } r;
  r.u[0] = f2bf(a.x); r.u[1] = f2bf(a.y); r.u[2] = f2bf(a.z); r.u[3] = f2bf(a.w);
  r.u[4] = f2bf(b.x); r.u[5] = f2bf(b.y); r.u[6] = f2bf(b.z); r.u[7] = f2bf(b.w);
  *reinterpret_cast<short8*>(out + i) = r.v;
}

// ---------------- bf16 GEMM: C[M,N] = A[M,K] * Bw[N,K]^T (f32 out) ----------------
// R23: 64x128 tiles, 256-thread/4-wave blocks -> grid 1024, 6 blocks/CU
// resident (24.5KB LDS) = 24 waves/CU (was 2 blocks x 8 waves = 16, grid-
// limited). Single-buffer 2-barrier loop (R15-validated; counted-vmcnt was
// neutral, R17). NT C stores kept.
__global__ __launch_bounds__(256) void gemm_bt(const u16* __restrict__ A,
                                               const u16* __restrict__ Bw,
                                               float* __restrict__ C, int M,
                                               int N, int K) {
  __shared__ u16 As[64 * 64];
  __shared__ u16 Bs[128 * 64];
  const int tid = threadIdx.x;
  const int lane = tid & 63;
  const int wave = tid >> 6;      // 0..3
  const int ntile = N >> 7;       // 16
  const int m0 = (blockIdx.x / ntile) << 6;   // 64-row tiles
  const int n0 = (blockIdx.x % ntile) << 7;
  const int wr = (wave >> 1) << 5;  // 0,32
  const int wc = (wave & 1) << 6;   // 0,64
  const int arow = lane & 15;
  const int kgrp = lane >> 4;

  const f32x4 zero4 = {0.f, 0.f, 0.f, 0.f};
  f32x4 acc[2][4];
#pragma unroll
  for (int m = 0; m < 2; m++)
#pragma unroll
    for (int n = 0; n < 4; n++) acc[m][n] = zero4;

  // A: 64x64 = 512 loads (2/thread); B: 128x64 = 1024 loads (4/thread)
  int srowA[2], sslotA[2], srowB[4], sslotB[4];
#pragma unroll
  for (int i = 0; i < 2; i++) {
    int c = i * 256 + tid;
    srowA[i] = c >> 3;
    sslotA[i] = (c & 7) ^ (srowA[i] & 7);
  }
#pragma unroll
  for (int i = 0; i < 4; i++) {
    int c = i * 256 + tid;
    srowB[i] = c >> 3;
    sslotB[i] = (c & 7) ^ (srowB[i] & 7);
  }

  auto stage = [&](int kt) {
    const int k0 = kt << 6;
#pragma unroll
    for (int i = 0; i < 2; i++) {
      const u16* ga = A + (size_t)(m0 + srowA[i]) * K + k0 + sslotA[i] * 8;
      GLDS16(ga, As + (i * 256 + tid) * 8);
    }
#pragma unroll
    for (int i = 0; i < 4; i++) {
      const u16* gb = Bw + (size_t)(n0 + srowB[i]) * K + k0 + sslotB[i] * 8;
      GLDS16(gb, Bs + (i * 256 + tid) * 8);
    }
  };

  const int KT = K >> 6;
  stage(0);
  for (int kt = 0;; kt++) {
    __syncthreads();
#pragma unroll
    for (int ks = 0; ks < 2; ks++) {
      const int sd = ks * 4 + kgrp;
      short8 a[2], b[4];
#pragma unroll
      for (int m = 0; m < 2; m++) {
        int r = wr + m * 16 + arow;
        a[m] = *reinterpret_cast<const short8*>(As + r * 64 + ((sd ^ (r & 7)) << 3));
      }
#pragma unroll
      for (int n = 0; n < 4; n++) {
        int r = wc + n * 16 + arow;
        b[n] = *reinterpret_cast<const short8*>(Bs + r * 64 + ((sd ^ (r & 7)) << 3));
      }
#pragma unroll
      for (int m = 0; m < 2; m++)
#pragma unroll
        for (int n = 0; n < 4; n++)
          acc[m][n] = __builtin_amdgcn_mfma_f32_16x16x32_bf16(a[m], b[n], acc[m][n], 0, 0, 0);
    }
    if (kt + 1 == KT) break;
    __syncthreads();
    stage(kt + 1);
  }

  const int crow = kgrp * 4;
#pragma unroll
  for (int m = 0; m < 2; m++) {
#pragma unroll
    for (int n = 0; n < 4; n++) {
      float* cp = C + (size_t)(m0 + wr + m * 16 + crow) * N + n0 + wc + n * 16 + arow;
#pragma unroll
      for (int r = 0; r < 4; r++)
        __builtin_nontemporal_store(acc[m][n][r], cp + (size_t)r * N);
    }
  }
}

// ---------------- fused QKV GEMM: proj + RoPE + RMSNorm + pack + V outputs ----
// R19/R21-validated. Unchanged.
__global__ __launch_bounds__(512) void gemm_qkv(
    const u16* __restrict__ A, const u16* __restrict__ Bw,
    const float* __restrict__ tct, const float* __restrict__ tst,
    const float* __restrict__ gain, u16* __restrict__ Vt,
    float* __restrict__ Vout, u16* __restrict__ Qn, u16* __restrict__ Kn) {
  __shared__ u16 As[128 * 64];
  __shared__ u16 Bs[128 * 64];
  const int tid = threadIdx.x;
  const int lane = tid & 63;
  const int wave = tid >> 6;      // 0..7
  const int ntile = PROJN >> 7;   // 24
  const int m0 = (blockIdx.x / ntile) << 7;
  const int n0 = (blockIdx.x % ntile) << 7;
  const int wr = (wave >> 1) << 5;  // 0,32,64,96
  const int wc = (wave & 1) << 6;   // 0,64
  const int ql = lane & 15;
  const int g = lane >> 4;
  const int K = 2048;

  const f32x4 zero4 = {0.f, 0.f, 0.f, 0.f};
  f32x4 acc[2][4];
#pragma unroll
  for (int m = 0; m < 2; m++)
#pragma unroll
    for (int n = 0; n < 4; n++) acc[m][n] = zero4;

  int srow[2], sslot[2];
#pragma unroll
  for (int i = 0; i < 2; i++) {
    int c = i * 512 + tid;
    srow[i] = c >> 3;
    sslot[i] = (c & 7) ^ (srow[i] & 7);
  }

  auto stage = [&](int kt) {
    const int k0 = kt << 6;
#pragma unroll
    for (int i = 0; i < 2; i++) {
      const u16* ga = A + (size_t)(m0 + srow[i]) * K + k0 + sslot[i] * 8;
      GLDS16(ga, As + (i * 512 + tid) * 8);
    }
#pragma unroll
    for (int i = 0; i < 2; i++) {
      const u16* gb = Bw + (size_t)(n0 + srow[i]) * K + k0 + sslot[i] * 8;
      GLDS16(gb, Bs + (i * 512 + tid) * 8);
    }
  };

  stage(0);
  for (int kt = 0;; kt++) {
    __syncthreads();
#pragma unroll
    for (int ks = 0; ks < 2; ks++) {
      const int sd = ks * 4 + g;
      short8 a[2], b[4];
#pragma unroll
      for (int m = 0; m < 2; m++) {
        int r = wr + m * 16 + ql;
        a[m] = *reinterpret_cast<const short8*>(As + r * 64 + ((sd ^ (r & 7)) << 3));
      }
#pragma unroll
      for (int n = 0; n < 4; n++) {
        int r = wc + n * 16 + ql;
        b[n] = *reinterpret_cast<const short8*>(Bs + r * 64 + ((sd ^ (r & 7)) << 3));
      }
#pragma unroll
      for (int m = 0; m < 2; m++)
#pragma unroll
        for (int n = 0; n < 4; n++)
          acc[m][n] = __builtin_amdgcn_mfma_f32_16x16x32_bf16(a[m], b[n], acc[m][n], 0, 0, 0);
    }
    if (kt + 1 == 32) break;
    __syncthreads();
    stage(kt + 1);
  }

  // ---- fused epilogue ----
  const int hslice = (n0 + wc) >> 6;     // 0..47
  const int browbase = m0 + wr + 4 * g;  // + 16m + r

  if (hslice >= 40) {
    const int kvh2 = hslice - 40;
#pragma unroll
    for (int m = 0; m < 2; m++) {
      const int rowg = browbase + 16 * m;
      const int sb = rowg & (S_ - 1);
      const int bb2 = rowg >> 11;
#pragma unroll
      for (int n = 0; n < 4; n++) {
        const int d = n * 16 + ql;
        union { short4v v; u16 uu[4]; } pv;
#pragma unroll
        for (int r = 0; r < 4; r++) pv.uu[r] = f2bf(acc[m][n][r]);
        *reinterpret_cast<short4v*>(
            Vt + (((size_t)(bb2 * KVH_ + kvh2)) * HD_ + d) * S_ + sb) = pv.v;
#pragma unroll
        for (int hh = 0; hh < 4; hh++) {
          float* vd = Vout +
              (((size_t)((kvh2 * 4 + hh) * B_ + bb2)) * S_ + sb) * HD_ + d;
#pragma unroll
          for (int r = 0; r < 4; r++)
            __builtin_nontemporal_store(acc[m][n][r], vd + (size_t)r * HD_);
        }
      }
    }
    return;
  }

  const int bb = (m0 + wr) >> 11;
  const bool isQ = (hslice < 32);
  const float scale = isQ ? gain[0] * 0.18033688011112042f : 1.0f;
  u16* outp = isQ ? Qn + ((size_t)(bb * H_ + hslice)) * S_ * HD_
                  : Kn + ((size_t)(bb * KVH_ + (hslice - 32))) * S_ * HD_;
  const int jj0 = ql, jj1 = 16 + ql;

#pragma unroll
  for (int m = 0; m < 2; m++) {
    const int sb = (browbase + 16 * m) & (S_ - 1);
    float c0a[4], c1a[4], s0a[4], s1a[4];
    *reinterpret_cast<float4*>(c0a) = *reinterpret_cast<const float4*>(&tct[jj0 * 2048 + sb]);
    *reinterpret_cast<float4*>(c1a) = *reinterpret_cast<const float4*>(&tct[jj1 * 2048 + sb]);
    *reinterpret_cast<float4*>(s0a) = *reinterpret_cast<const float4*>(&tst[jj0 * 2048 + sb]);
    *reinterpret_cast<float4*>(s1a) = *reinterpret_cast<const float4*>(&tst[jj1 * 2048 + sb]);
    float o[4][4], iv[4];
#pragma unroll
    for (int r = 0; r < 4; r++) {
      const float a0 = acc[m][0][r], a1 = acc[m][1][r];
      const float a2 = acc[m][2][r], a3 = acc[m][3][r];
      const float l0 = a0 * c0a[r] - a2 * s0a[r];
      const float l1 = a1 * c1a[r] - a3 * s1a[r];
      const float h0 = a2 * c0a[r] + a0 * s0a[r];
      const float h1 = a3 * c1a[r] + a1 * s1a[r];
      o[0][r] = l0; o[1][r] = l1; o[2][r] = h0; o[3][r] = h1;
      float sr = (l0 * l0 + l1 * l1) + (h0 * h0 + h1 * h1);
      sr += __shfl_xor(sr, 1);
      sr += __shfl_xor(sr, 2);
      sr += __shfl_xor(sr, 4);
      sr += __shfl_xor(sr, 8);
      iv[r] = rsqrtf(sr * (1.0f / 64.0f) + 1e-6f) * scale;
    }
#pragma unroll
    for (int n = 0; n < 4; n++) {
      const int d = n * 16 + ql;
#pragma unroll
      for (int r = 0; r < 4; r++)
        outp[(size_t)(sb + r) * HD_ + d] = f2bf(o[n][r] * iv[r]);
    }
  }
}

// ---------------- flash attention (causal, GQA) + tail wout pack ------------
// R22-validated: counted-vmcnt K/V dbuf + wout-pack blocks >=1024. Unchanged.
__global__ __launch_bounds__(256, 2) void attn_fwd(
    const u16* __restrict__ Qn, const u16* __restrict__ Kn,
    const u16* __restrict__ Vt, u16* __restrict__ Aout,
    const float* __restrict__ wout, u16* __restrict__ woutb) {
  const int bid = blockIdx.x;  // 1024 attn + 2048 pack
  if (bid >= 1024) {
    const int i = ((bid - 1024) * 256 + threadIdx.x) * 8;
    const float4* p = reinterpret_cast<const float4*>(wout + i);
    float4 a = p[0], b = p[1];
    union { short8 v; u16 u[8]; } r;
    r.u[0] = f2bf(a.x); r.u[1] = f2bf(a.y); r.u[2] = f2bf(a.z); r.u[3] = f2bf(a.w);
    r.u[4] = f2bf(b.x); r.u[5] = f2bf(b.y); r.u[6] = f2bf(b.z); r.u[7] = f2bf(b.w);
    *reinterpret_cast<short8*>(woutb + i) = r.v;
    return;
  }
  __shared__ u16 Ks[2][64 * 64];
  __shared__ u16 Vs[2][64 * 64];
  __shared__ u16 Ps[4][1024];
  const int grp = bid & 15;
  const int i = bid >> 4;
  const int qt = 63 - i;  // LPT: longest first
  const int b = grp >> 3;
  const int kvh = grp & 7;
  const int q0 = qt << 5;
  const int JT = (qt >> 1) + 1;
  const int tid = threadIdx.x;
  const int lane = tid & 63;
  const int wave = tid >> 6;
  const int h = kvh * 4 + wave;
  const int ql = lane & 15;
  const int g = lane >> 4;

  short8 qa[2][2];
  int rowq[2];
#pragma unroll
  for (int f = 0; f < 2; f++) {
    rowq[f] = q0 + 16 * f + ql;
    const u16* qb = Qn + (((size_t)(b * H_ + h)) * S_ + rowq[f]) * HD_;
    qa[f][0] = *reinterpret_cast<const short8*>(qb + g * 8);
    qa[f][1] = *reinterpret_cast<const short8*>(qb + 32 + g * 8);
  }

  const f32x4 zero4 = {0.f, 0.f, 0.f, 0.f};
  f32x4 oacc[4][2];
#pragma unroll
  for (int dn = 0; dn < 4; dn++)
#pragma unroll
    for (int f = 0; f < 2; f++) oacc[dn][f] = zero4;
  float psum[2] = {0.f, 0.f};

  const u16* kg = Kn + ((size_t)(b * KVH_ + kvh)) * S_ * HD_;
  const u16* vg = Vt + ((size_t)(b * KVH_ + kvh)) * HD_ * S_;

  const int c0 = tid, c1 = 256 + tid;
  const int r0 = c0 >> 3, sl0 = (c0 & 7) ^ (r0 & 7);
  const int r1 = c1 >> 3, sl1 = (c1 & 7) ^ (r1 & 7);
  const int xsw2 = (ql & 7) << 2;

  auto stage = [&](int jt, int buf) {
    const int j0 = jt << 6;
    GLDS16(kg + (size_t)(j0 + r0) * HD_ + sl0 * 8, Ks[buf] + c0 * 8);
    GLDS16(kg + (size_t)(j0 + r1) * HD_ + sl1 * 8, Ks[buf] + c1 * 8);
    GLDS16(vg + (size_t)r0 * S_ + j0 + sl0 * 8, Vs[buf] + c0 * 8);
    GLDS16(vg + (size_t)r1 * S_ + j0 + sl1 * 8, Vs[buf] + c1 * 8);
  };

  stage(0, 0);
  if (JT > 1) stage(1, 1);  // 8 loads/thread in flight
  int cur = 0;
  for (int jt = 0; jt < JT; jt++) {
    if (jt + 1 < JT) asm volatile("s_waitcnt vmcnt(4)" ::: "memory");
    else             asm volatile("s_waitcnt vmcnt(0)" ::: "memory");
    __builtin_amdgcn_s_barrier();
    __builtin_amdgcn_sched_barrier(0);
    const int j0 = jt << 6;
    const u16* ksb = Ks[cur];
    const u16* vsb = Vs[cur];
    const bool diag = (jt == JT - 1);

    f32x4 sc[4][2];
#pragma unroll
    for (int n = 0; n < 4; n++)
#pragma unroll
      for (int f = 0; f < 2; f++) sc[n][f] = zero4;
    __builtin_amdgcn_s_setprio(1);
#pragma unroll
    for (int ks = 0; ks < 2; ks++) {
      const int sd = ks * 4 + g;
#pragma unroll
      for (int n = 0; n < 4; n++) {
        const int r = n * 16 + ql;
        short8 kf = *reinterpret_cast<const short8*>(ksb + r * 64 + ((sd ^ (r & 7)) << 3));
        sc[n][0] = __builtin_amdgcn_mfma_f32_16x16x32_bf16(kf, qa[0][ks], sc[n][0], 0, 0, 0);
        sc[n][1] = __builtin_amdgcn_mfma_f32_16x16x32_bf16(kf, qa[1][ks], sc[n][1], 0, 0, 0);
      }
    }
    __builtin_amdgcn_s_setprio(0);

    short8 pa[2][2];
#pragma unroll
    for (int f = 0; f < 2; f++) {
      float pv[4][4];
#pragma unroll
      for (int n = 0; n < 4; n++)
#pragma unroll
        for (int r = 0; r < 4; r++)
          pv[n][r] = fast_exp2(sc[n][f][r]);  // Q prescaled; bias cancels
      if (diag) {
#pragma unroll
        for (int n = 0; n < 4; n++)
#pragma unroll
          for (int r = 0; r < 4; r++)
            if ((j0 + n * 16 + 4 * g + r) > rowq[f]) pv[n][r] = 0.f;
      }
      u32* pw32 = reinterpret_cast<u32*>(Ps[wave]);
#pragma unroll
      for (int n = 0; n < 4; n++) {
        psum[f] += (pv[n][0] + pv[n][1]) + (pv[n][2] + pv[n][3]);
        const int idx = ql * 32 + (((n << 3) + (g << 1)) ^ xsw2);
        pw32[idx] = pack2bf(pv[n][0], pv[n][1]);
        pw32[idx + 1] = pack2bf(pv[n][2], pv[n][3]);
      }
#pragma unroll
      for (int ks = 0; ks < 2; ks++)
        pa[f][ks] = *reinterpret_cast<const short8*>(
            Ps[wave] + ql * 64 + ((32 * ks + 8 * g) ^ (xsw2 << 1)));
    }

    __builtin_amdgcn_s_setprio(1);
#pragma unroll
    for (int ks = 0; ks < 2; ks++) {
      const int sd = ks * 4 + g;
#pragma unroll
      for (int dn = 0; dn < 4; dn++) {
        const int vr = dn * 16 + ql;
        short8 vf = *reinterpret_cast<const short8*>(vsb + vr * 64 + ((sd ^ (vr & 7)) << 3));
        oacc[dn][0] = __builtin_amdgcn_mfma_f32_16x16x32_bf16(vf, pa[0][ks], oacc[dn][0], 0, 0, 0);
        oacc[dn][1] = __builtin_amdgcn_mfma_f32_16x16x32_bf16(vf, pa[1][ks], oacc[dn][1], 0, 0, 0);
      }
    }
    __builtin_amdgcn_s_setprio(0);

    __builtin_amdgcn_sched_barrier(0);
    __builtin_amdgcn_s_barrier();  // all waves done reading buf[cur]
    if (jt + 2 < JT) stage(jt + 2, cur);
    cur ^= 1;
  }

#pragma unroll
  for (int f = 0; f < 2; f++) {
    float s = psum[f];
    s += __shfl_xor(s, 16);
    s += __shfl_xor(s, 32);
    const float il = 1.0f / s;
#pragma unroll
    for (int dn = 0; dn < 4; dn++) {
      union { short4v v; u16 uu[4]; } o;
#pragma unroll
      for (int r = 0; r < 4; r++) o.uu[r] = f2bf(oacc[dn][f][r] * il);
      u16* dst = Aout + ((size_t)b * S_ + rowq[f]) * D_ + h * HD_ + dn * 16 + 4 * g;
      *reinterpret_cast<short4v*>(dst) = o.v;
    }
  }
}

// ---------------- launcher ----------------
extern "C" void kernel_launch(void* const* d_in, const int* in_sizes, int n_in,
                              void* d_out, int out_size, void* d_ws,
                              size_t ws_size, hipStream_t stream) {
  const float* x = (const float*)d_in[0];
  const float* wqkv = (const float*)d_in[1];
  const float* wout = (const float*)d_in[2];
  const float* gain = (const float*)d_in[3];

  float* out_attn = (float*)d_out;                       // (B,S,D) f32
  float* out_vflat = out_attn + (size_t)B_ * S_ * D_;    // (H*B,S,HD) f32

  uint8_t* w = (uint8_t*)d_ws;
  u16* xb      = (u16*)(w);                     // 16,777,216 B
  u16* wqkvb   = (u16*)(w + 16777216);          // 12,582,912 B
  u16* woutb   = (u16*)(w + 29360128);          //  8,388,608 B
  u16* Qn      = (u16*)(w + 37748736);          // 16,777,216 B
  u16* Kn      = (u16*)(w + 54525952);          //  4,194,304 B
  u16* Vt      = (u16*)(w + 58720256);          //  4,194,304 B
  u16* attnb   = (u16*)(w + 62914560);          // 16,777,216 B
  float* tct   = (float*)(w + 79691776);        //    262,144 B
  float* tst   = (float*)(w + 79953920);        //    262,144 B
  // total: 80,216,064 B

  pack3<<<7424, 256, 0, stream>>>(x, wqkv, xb, wqkvb, tct, tst);

  // fused: proj + rope + rmsnorm + prescale + pack + V outputs
  gemm_qkv<<<(4096 / 128) * (3072 / 128), 512, 0, stream>>>(
      xb, wqkvb, tct, tst, gain, Vt, out_vflat, Qn, Kn);
  // attn (1024 LPT blocks) + wout pack tail (2048 blocks)
  attn_fwd<<<1024 + 2048, 256, 0, stream>>>(Qn, Kn, Vt, attnb, wout, woutb);
  // attn_out = attn @ w_out^T : 64x128 tiles -> (4096/64)*(2048/128) = 1024
  gemm_bt<<<(4096 / 64) * (2048 / 128), 256, 0, stream>>>(attnb, woutb,
                                                          out_attn, 4096,
                                                          2048, 2048);
}

// Round 24
// 176.271 us; speedup vs baseline: 1.0350x; 1.0350x over previous
//
#include <hip/hip_runtime.h>
#include <hip/hip_bf16.h>
#include <cstdint>
#include <cstddef>

#define B_ 2
#define S_ 2048
#define D_ 2048
#define H_ 32
#define KVH_ 8
#define HD_ 64
#define PROJN 3072   // Q_OUT(2048) + 2*KV_OUT(512)

typedef unsigned short u16;
typedef unsigned int u32;
typedef __attribute__((ext_vector_type(8))) short short8;
typedef __attribute__((ext_vector_type(4))) short short4v;
typedef __attribute__((ext_vector_type(4))) float f32x4;

__device__ __forceinline__ u16 f2bf(float f) {
  __hip_bfloat16 h = __float2bfloat16(f);
  return *reinterpret_cast<u16*>(&h);
}

// raw v_exp_f32 (2^x): avoids ocml exp2f libcall expansion (~25 VALU ops)
__device__ __forceinline__ float fast_exp2(float x) {
  float r;
  asm("v_exp_f32 %0, %1" : "=v"(r) : "v"(x));
  return r;
}

// pack two f32 -> two bf16 (round-half-up) in one u32: 2 adds + 1 perm
__device__ __forceinline__ u32 pack2bf(float lo, float hi) {
  u32 a = __float_as_uint(lo) + 0x8000u;
  u32 b = __float_as_uint(hi) + 0x8000u;
  return __builtin_amdgcn_perm(b, a, 0x07060302);  // {b[31:16], a[31:16]}
}

#define GLDS16(g, l)                                                           \
  __builtin_amdgcn_global_load_lds(                                            \
      (const __attribute__((address_space(1))) void*)(g),                      \
      (__attribute__((address_space(3))) void*)(l), 16, 0, 0)

// ---------------- pack f32 -> bf16 (x, w_qkv) + rope tables (one launch) ----
__global__ __launch_bounds__(256) void pack3(const float* __restrict__ x,
                                             const float* __restrict__ wqkv,
                                             u16* __restrict__ xb,
                                             u16* __restrict__ wqkvb,
                                             float* __restrict__ tct,
                                             float* __restrict__ tst) {
  const int bid = blockIdx.x;  // 4096 + 3072 = 7168 pack + 256 tab
  if (bid >= 7168) {
    int i = (bid - 7168) * 256 + threadIdx.x;  // 32*2048
    int j = i >> 11, s = i & 2047;
    float e = (float)(2 * j) / 64.0f;
    float inv_freq = 1.0f / powf(10000.0f, e);
    float ang = (float)s * inv_freq;
    tct[i] = cosf(ang);
    tst[i] = sinf(ang);
    return;
  }
  const float* in;
  u16* out;
  int base;
  if (bid < 4096) { in = x; out = xb; base = bid; }
  else { in = wqkv; out = wqkvb; base = bid - 4096; }
  const int i = (base * 256 + threadIdx.x) * 8;
  const float4* p = reinterpret_cast<const float4*>(in + i);
  float4 a = p[0], b = p[1];
  union { short8 v; u16 u[8]; } r;
  r.u[0] = f2bf(a.x); r.u[1] = f2bf(a.y); r.u[2] = f2bf(a.z); r.u[3] = f2bf(a.w);
  r.u[4] = f2bf(b.x); r.u[5] = f2bf(b.y); r.u[6] = f2bf(b.z); r.u[7] = f2bf(b.w);
  *reinterpret_cast<short8*>(out + i) = r.v;
}

// ---------------- bf16 GEMM: C[M,N] = A[M,K] * Bw[N,K]^T (f32 out) ----------------
// R22-validated form (R17 counted-vmcnt dbuf, 128^2 tile, 8 waves, NT C
// stores). R23's 64x128 retile regressed ~5us -> reverted.
__global__ __launch_bounds__(512) void gemm_bt(const u16* __restrict__ A,
                                               const u16* __restrict__ Bw,
                                               float* __restrict__ C, int M,
                                               int N, int K) {
  __shared__ u16 As[2][128 * 64];
  __shared__ u16 Bs[2][128 * 64];
  const int tid = threadIdx.x;
  const int lane = tid & 63;
  const int wave = tid >> 6;      // 0..7
  const int ntile = N >> 7;
  const int m0 = (blockIdx.x / ntile) << 7;
  const int n0 = (blockIdx.x % ntile) << 7;
  const int wr = (wave >> 1) << 5;  // 0,32,64,96
  const int wc = (wave & 1) << 6;   // 0,64
  const int arow = lane & 15;
  const int kgrp = lane >> 4;

  const f32x4 zero4 = {0.f, 0.f, 0.f, 0.f};
  f32x4 acc[2][4];
#pragma unroll
  for (int m = 0; m < 2; m++)
#pragma unroll
    for (int n = 0; n < 4; n++) acc[m][n] = zero4;

  int srow[2], sslot[2];
#pragma unroll
  for (int i = 0; i < 2; i++) {
    int c = i * 512 + tid;
    srow[i] = c >> 3;
    sslot[i] = (c & 7) ^ (srow[i] & 7);
  }

  auto stage = [&](int kt, int buf) {
    const int k0 = kt << 6;
#pragma unroll
    for (int i = 0; i < 2; i++) {
      const u16* ga = A + (size_t)(m0 + srow[i]) * K + k0 + sslot[i] * 8;
      GLDS16(ga, As[buf] + (i * 512 + tid) * 8);
    }
#pragma unroll
    for (int i = 0; i < 2; i++) {
      const u16* gb = Bw + (size_t)(n0 + srow[i]) * K + k0 + sslot[i] * 8;
      GLDS16(gb, Bs[buf] + (i * 512 + tid) * 8);
    }
  };

  const int KT = K >> 6;
  stage(0, 0);
  stage(1, 1);  // 8 loads/thread in flight
  int cur = 0;
  for (int kt = 0; kt < KT; kt++) {
    if (kt + 1 < KT) asm volatile("s_waitcnt vmcnt(4)" ::: "memory");
    else             asm volatile("s_waitcnt vmcnt(0)" ::: "memory");
    __builtin_amdgcn_s_barrier();
    __builtin_amdgcn_sched_barrier(0);
    const u16* Asb = As[cur];
    const u16* Bsb = Bs[cur];
#pragma unroll
    for (int ks = 0; ks < 2; ks++) {
      const int sd = ks * 4 + kgrp;
      short8 a[2], b[4];
#pragma unroll
      for (int m = 0; m < 2; m++) {
        int r = wr + m * 16 + arow;
        a[m] = *reinterpret_cast<const short8*>(Asb + r * 64 + ((sd ^ (r & 7)) << 3));
      }
#pragma unroll
      for (int n = 0; n < 4; n++) {
        int r = wc + n * 16 + arow;
        b[n] = *reinterpret_cast<const short8*>(Bsb + r * 64 + ((sd ^ (r & 7)) << 3));
      }
#pragma unroll
      for (int m = 0; m < 2; m++)
#pragma unroll
        for (int n = 0; n < 4; n++)
          acc[m][n] = __builtin_amdgcn_mfma_f32_16x16x32_bf16(a[m], b[n], acc[m][n], 0, 0, 0);
    }
    __builtin_amdgcn_sched_barrier(0);
    __builtin_amdgcn_s_barrier();
    if (kt + 2 < KT) stage(kt + 2, cur);
    cur ^= 1;
  }

  const int crow = kgrp * 4;
#pragma unroll
  for (int m = 0; m < 2; m++) {
#pragma unroll
    for (int n = 0; n < 4; n++) {
      float* cp = C + (size_t)(m0 + wr + m * 16 + crow) * N + n0 + wc + n * 16 + arow;
#pragma unroll
      for (int r = 0; r < 4; r++)
        __builtin_nontemporal_store(acc[m][n][r], cp + (size_t)r * N);
    }
  }
}

// ---------------- fused QKV GEMM: proj + RoPE + RMSNorm + pack + V outputs ----
// R19/R21-validated. Unchanged.
__global__ __launch_bounds__(512) void gemm_qkv(
    const u16* __restrict__ A, const u16* __restrict__ Bw,
    const float* __restrict__ tct, const float* __restrict__ tst,
    const float* __restrict__ gain, u16* __restrict__ Vt,
    float* __restrict__ Vout, u16* __restrict__ Qn, u16* __restrict__ Kn) {
  __shared__ u16 As[128 * 64];
  __shared__ u16 Bs[128 * 64];
  const int tid = threadIdx.x;
  const int lane = tid & 63;
  const int wave = tid >> 6;      // 0..7
  const int ntile = PROJN >> 7;   // 24
  const int m0 = (blockIdx.x / ntile) << 7;
  const int n0 = (blockIdx.x % ntile) << 7;
  const int wr = (wave >> 1) << 5;  // 0,32,64,96
  const int wc = (wave & 1) << 6;   // 0,64
  const int ql = lane & 15;
  const int g = lane >> 4;
  const int K = 2048;

  const f32x4 zero4 = {0.f, 0.f, 0.f, 0.f};
  f32x4 acc[2][4];
#pragma unroll
  for (int m = 0; m < 2; m++)
#pragma unroll
    for (int n = 0; n < 4; n++) acc[m][n] = zero4;

  int srow[2], sslot[2];
#pragma unroll
  for (int i = 0; i < 2; i++) {
    int c = i * 512 + tid;
    srow[i] = c >> 3;
    sslot[i] = (c & 7) ^ (srow[i] & 7);
  }

  auto stage = [&](int kt) {
    const int k0 = kt << 6;
#pragma unroll
    for (int i = 0; i < 2; i++) {
      const u16* ga = A + (size_t)(m0 + srow[i]) * K + k0 + sslot[i] * 8;
      GLDS16(ga, As + (i * 512 + tid) * 8);
    }
#pragma unroll
    for (int i = 0; i < 2; i++) {
      const u16* gb = Bw + (size_t)(n0 + srow[i]) * K + k0 + sslot[i] * 8;
      GLDS16(gb, Bs + (i * 512 + tid) * 8);
    }
  };

  stage(0);
  for (int kt = 0;; kt++) {
    __syncthreads();
#pragma unroll
    for (int ks = 0; ks < 2; ks++) {
      const int sd = ks * 4 + g;
      short8 a[2], b[4];
#pragma unroll
      for (int m = 0; m < 2; m++) {
        int r = wr + m * 16 + ql;
        a[m] = *reinterpret_cast<const short8*>(As + r * 64 + ((sd ^ (r & 7)) << 3));
      }
#pragma unroll
      for (int n = 0; n < 4; n++) {
        int r = wc + n * 16 + ql;
        b[n] = *reinterpret_cast<const short8*>(Bs + r * 64 + ((sd ^ (r & 7)) << 3));
      }
#pragma unroll
      for (int m = 0; m < 2; m++)
#pragma unroll
        for (int n = 0; n < 4; n++)
          acc[m][n] = __builtin_amdgcn_mfma_f32_16x16x32_bf16(a[m], b[n], acc[m][n], 0, 0, 0);
    }
    if (kt + 1 == 32) break;
    __syncthreads();
    stage(kt + 1);
  }

  // ---- fused epilogue ----
  const int hslice = (n0 + wc) >> 6;     // 0..47
  const int browbase = m0 + wr + 4 * g;  // + 16m + r

  if (hslice >= 40) {
    const int kvh2 = hslice - 40;
#pragma unroll
    for (int m = 0; m < 2; m++) {
      const int rowg = browbase + 16 * m;
      const int sb = rowg & (S_ - 1);
      const int bb2 = rowg >> 11;
#pragma unroll
      for (int n = 0; n < 4; n++) {
        const int d = n * 16 + ql;
        union { short4v v; u16 uu[4]; } pv;
#pragma unroll
        for (int r = 0; r < 4; r++) pv.uu[r] = f2bf(acc[m][n][r]);
        *reinterpret_cast<short4v*>(
            Vt + (((size_t)(bb2 * KVH_ + kvh2)) * HD_ + d) * S_ + sb) = pv.v;
#pragma unroll
        for (int hh = 0; hh < 4; hh++) {
          float* vd = Vout +
              (((size_t)((kvh2 * 4 + hh) * B_ + bb2)) * S_ + sb) * HD_ + d;
#pragma unroll
          for (int r = 0; r < 4; r++)
            __builtin_nontemporal_store(acc[m][n][r], vd + (size_t)r * HD_);
        }
      }
    }
    return;
  }

  const int bb = (m0 + wr) >> 11;
  const bool isQ = (hslice < 32);
  const float scale = isQ ? gain[0] * 0.18033688011112042f : 1.0f;
  u16* outp = isQ ? Qn + ((size_t)(bb * H_ + hslice)) * S_ * HD_
                  : Kn + ((size_t)(bb * KVH_ + (hslice - 32))) * S_ * HD_;
  const int jj0 = ql, jj1 = 16 + ql;

#pragma unroll
  for (int m = 0; m < 2; m++) {
    const int sb = (browbase + 16 * m) & (S_ - 1);
    float c0a[4], c1a[4], s0a[4], s1a[4];
    *reinterpret_cast<float4*>(c0a) = *reinterpret_cast<const float4*>(&tct[jj0 * 2048 + sb]);
    *reinterpret_cast<float4*>(c1a) = *reinterpret_cast<const float4*>(&tct[jj1 * 2048 + sb]);
    *reinterpret_cast<float4*>(s0a) = *reinterpret_cast<const float4*>(&tst[jj0 * 2048 + sb]);
    *reinterpret_cast<float4*>(s1a) = *reinterpret_cast<const float4*>(&tst[jj1 * 2048 + sb]);
    float o[4][4], iv[4];
#pragma unroll
    for (int r = 0; r < 4; r++) {
      const float a0 = acc[m][0][r], a1 = acc[m][1][r];
      const float a2 = acc[m][2][r], a3 = acc[m][3][r];
      const float l0 = a0 * c0a[r] - a2 * s0a[r];
      const float l1 = a1 * c1a[r] - a3 * s1a[r];
      const float h0 = a2 * c0a[r] + a0 * s0a[r];
      const float h1 = a3 * c1a[r] + a1 * s1a[r];
      o[0][r] = l0; o[1][r] = l1; o[2][r] = h0; o[3][r] = h1;
      float sr = (l0 * l0 + l1 * l1) + (h0 * h0 + h1 * h1);
      sr += __shfl_xor(sr, 1);
      sr += __shfl_xor(sr, 2);
      sr += __shfl_xor(sr, 4);
      sr += __shfl_xor(sr, 8);
      iv[r] = rsqrtf(sr * (1.0f / 64.0f) + 1e-6f) * scale;
    }
#pragma unroll
    for (int n = 0; n < 4; n++) {
      const int d = n * 16 + ql;
#pragma unroll
      for (int r = 0; r < 4; r++)
        outp[(size_t)(sb + r) * HD_ + d] = f2bf(o[n][r] * iv[r]);
    }
  }
}

// ---------------- flash attention (causal, GQA) + tail wout pack ------------
// R22-validated: counted-vmcnt K/V dbuf + wout-pack blocks >=1024. Unchanged.
__global__ __launch_bounds__(256, 2) void attn_fwd(
    const u16* __restrict__ Qn, const u16* __restrict__ Kn,
    const u16* __restrict__ Vt, u16* __restrict__ Aout,
    const float* __restrict__ wout, u16* __restrict__ woutb) {
  const int bid = blockIdx.x;  // 1024 attn + 2048 pack
  if (bid >= 1024) {
    const int i = ((bid - 1024) * 256 + threadIdx.x) * 8;
    const float4* p = reinterpret_cast<const float4*>(wout + i);
    float4 a = p[0], b = p[1];
    union { short8 v; u16 u[8]; } r;
    r.u[0] = f2bf(a.x); r.u[1] = f2bf(a.y); r.u[2] = f2bf(a.z); r.u[3] = f2bf(a.w);
    r.u[4] = f2bf(b.x); r.u[5] = f2bf(b.y); r.u[6] = f2bf(b.z); r.u[7] = f2bf(b.w);
    *reinterpret_cast<short8*>(woutb + i) = r.v;
    return;
  }
  __shared__ u16 Ks[2][64 * 64];
  __shared__ u16 Vs[2][64 * 64];
  __shared__ u16 Ps[4][1024];
  const int grp = bid & 15;
  const int i = bid >> 4;
  const int qt = 63 - i;  // LPT: longest first
  const int b = grp >> 3;
  const int kvh = grp & 7;
  const int q0 = qt << 5;
  const int JT = (qt >> 1) + 1;
  const int tid = threadIdx.x;
  const int lane = tid & 63;
  const int wave = tid >> 6;
  const int h = kvh * 4 + wave;
  const int ql = lane & 15;
  const int g = lane >> 4;

  short8 qa[2][2];
  int rowq[2];
#pragma unroll
  for (int f = 0; f < 2; f++) {
    rowq[f] = q0 + 16 * f + ql;
    const u16* qb = Qn + (((size_t)(b * H_ + h)) * S_ + rowq[f]) * HD_;
    qa[f][0] = *reinterpret_cast<const short8*>(qb + g * 8);
    qa[f][1] = *reinterpret_cast<const short8*>(qb + 32 + g * 8);
  }

  const f32x4 zero4 = {0.f, 0.f, 0.f, 0.f};
  f32x4 oacc[4][2];
#pragma unroll
  for (int dn = 0; dn < 4; dn++)
#pragma unroll
    for (int f = 0; f < 2; f++) oacc[dn][f] = zero4;
  float psum[2] = {0.f, 0.f};

  const u16* kg = Kn + ((size_t)(b * KVH_ + kvh)) * S_ * HD_;
  const u16* vg = Vt + ((size_t)(b * KVH_ + kvh)) * HD_ * S_;

  const int c0 = tid, c1 = 256 + tid;
  const int r0 = c0 >> 3, sl0 = (c0 & 7) ^ (r0 & 7);
  const int r1 = c1 >> 3, sl1 = (c1 & 7) ^ (r1 & 7);
  const int xsw2 = (ql & 7) << 2;

  auto stage = [&](int jt, int buf) {
    const int j0 = jt << 6;
    GLDS16(kg + (size_t)(j0 + r0) * HD_ + sl0 * 8, Ks[buf] + c0 * 8);
    GLDS16(kg + (size_t)(j0 + r1) * HD_ + sl1 * 8, Ks[buf] + c1 * 8);
    GLDS16(vg + (size_t)r0 * S_ + j0 + sl0 * 8, Vs[buf] + c0 * 8);
    GLDS16(vg + (size_t)r1 * S_ + j0 + sl1 * 8, Vs[buf] + c1 * 8);
  };

  stage(0, 0);
  if (JT > 1) stage(1, 1);  // 8 loads/thread in flight
  int cur = 0;
  for (int jt = 0; jt < JT; jt++) {
    if (jt + 1 < JT) asm volatile("s_waitcnt vmcnt(4)" ::: "memory");
    else             asm volatile("s_waitcnt vmcnt(0)" ::: "memory");
    __builtin_amdgcn_s_barrier();
    __builtin_amdgcn_sched_barrier(0);
    const int j0 = jt << 6;
    const u16* ksb = Ks[cur];
    const u16* vsb = Vs[cur];
    const bool diag = (jt == JT - 1);

    f32x4 sc[4][2];
#pragma unroll
    for (int n = 0; n < 4; n++)
#pragma unroll
      for (int f = 0; f < 2; f++) sc[n][f] = zero4;
    __builtin_amdgcn_s_setprio(1);
#pragma unroll
    for (int ks = 0; ks < 2; ks++) {
      const int sd = ks * 4 + g;
#pragma unroll
      for (int n = 0; n < 4; n++) {
        const int r = n * 16 + ql;
        short8 kf = *reinterpret_cast<const short8*>(ksb + r * 64 + ((sd ^ (r & 7)) << 3));
        sc[n][0] = __builtin_amdgcn_mfma_f32_16x16x32_bf16(kf, qa[0][ks], sc[n][0], 0, 0, 0);
        sc[n][1] = __builtin_amdgcn_mfma_f32_16x16x32_bf16(kf, qa[1][ks], sc[n][1], 0, 0, 0);
      }
    }
    __builtin_amdgcn_s_setprio(0);

    short8 pa[2][2];
#pragma unroll
    for (int f = 0; f < 2; f++) {
      float pv[4][4];
#pragma unroll
      for (int n = 0; n < 4; n++)
#pragma unroll
        for (int r = 0; r < 4; r++)
          pv[n][r] = fast_exp2(sc[n][f][r]);  // Q prescaled; bias cancels
      if (diag) {
#pragma unroll
        for (int n = 0; n < 4; n++)
#pragma unroll
          for (int r = 0; r < 4; r++)
            if ((j0 + n * 16 + 4 * g + r) > rowq[f]) pv[n][r] = 0.f;
      }
      u32* pw32 = reinterpret_cast<u32*>(Ps[wave]);
#pragma unroll
      for (int n = 0; n < 4; n++) {
        psum[f] += (pv[n][0] + pv[n][1]) + (pv[n][2] + pv[n][3]);
        const int idx = ql * 32 + (((n << 3) + (g << 1)) ^ xsw2);
        pw32[idx] = pack2bf(pv[n][0], pv[n][1]);
        pw32[idx + 1] = pack2bf(pv[n][2], pv[n][3]);
      }
#pragma unroll
      for (int ks = 0; ks < 2; ks++)
        pa[f][ks] = *reinterpret_cast<const short8*>(
            Ps[wave] + ql * 64 + ((32 * ks + 8 * g) ^ (xsw2 << 1)));
    }

    __builtin_amdgcn_s_setprio(1);
#pragma unroll
    for (int ks = 0; ks < 2; ks++) {
      const int sd = ks * 4 + g;
#pragma unroll
      for (int dn = 0; dn < 4; dn++) {
        const int vr = dn * 16 + ql;
        short8 vf = *reinterpret_cast<const short8*>(vsb + vr * 64 + ((sd ^ (vr & 7)) << 3));
        oacc[dn][0] = __builtin_amdgcn_mfma_f32_16x16x32_bf16(vf, pa[0][ks], oacc[dn][0], 0, 0, 0);
        oacc[dn][1] = __builtin_amdgcn_mfma_f32_16x16x32_bf16(vf, pa[1][ks], oacc[dn][1], 0, 0, 0);
      }
    }
    __builtin_amdgcn_s_setprio(0);

    __builtin_amdgcn_sched_barrier(0);
    __builtin_amdgcn_s_barrier();  // all waves done reading buf[cur]
    if (jt + 2 < JT) stage(jt + 2, cur);
    cur ^= 1;
  }

#pragma unroll
  for (int f = 0; f < 2; f++) {
    float s = psum[f];
    s += __shfl_xor(s, 16);
    s += __shfl_xor(s, 32);
    const float il = 1.0f / s;
#pragma unroll
    for (int dn = 0; dn < 4; dn++) {
      union { short4v v; u16 uu[4]; } o;
#pragma unroll
      for (int r = 0; r < 4; r++) o.uu[r] = f2bf(oacc[dn][f][r] * il);
      u16* dst = Aout + ((size_t)b * S_ + rowq[f]) * D_ + h * HD_ + dn * 16 + 4 * g;
      *reinterpret_cast<short4v*>(dst) = o.v;
    }
  }
}

// ---------------- launcher ----------------
extern "C" void kernel_launch(void* const* d_in, const int* in_sizes, int n_in,
                              void* d_out, int out_size, void* d_ws,
                              size_t ws_size, hipStream_t stream) {
  const float* x = (const float*)d_in[0];
  const float* wqkv = (const float*)d_in[1];
  const float* wout = (const float*)d_in[2];
  const float* gain = (const float*)d_in[3];

  float* out_attn = (float*)d_out;                       // (B,S,D) f32
  float* out_vflat = out_attn + (size_t)B_ * S_ * D_;    // (H*B,S,HD) f32

  uint8_t* w = (uint8_t*)d_ws;
  u16* xb      = (u16*)(w);                     // 16,777,216 B
  u16* wqkvb   = (u16*)(w + 16777216);          // 12,582,912 B
  u16* woutb   = (u16*)(w + 29360128);          //  8,388,608 B
  u16* Qn      = (u16*)(w + 37748736);          // 16,777,216 B
  u16* Kn      = (u16*)(w + 54525952);          //  4,194,304 B
  u16* Vt      = (u16*)(w + 58720256);          //  4,194,304 B
  u16* attnb   = (u16*)(w + 62914560);          // 16,777,216 B
  float* tct   = (float*)(w + 79691776);        //    262,144 B
  float* tst   = (float*)(w + 79953920);        //    262,144 B
  // total: 80,216,064 B

  pack3<<<7424, 256, 0, stream>>>(x, wqkv, xb, wqkvb, tct, tst);

  // fused: proj + rope + rmsnorm + prescale + pack + V outputs
  gemm_qkv<<<(4096 / 128) * (3072 / 128), 512, 0, stream>>>(
      xb, wqkvb, tct, tst, gain, Vt, out_vflat, Qn, Kn);
  // attn (1024 LPT blocks) + wout pack tail (2048 blocks)
  attn_fwd<<<1024 + 2048, 256, 0, stream>>>(Qn, Kn, Vt, attnb, wout, woutb);
  // attn_out = attn @ w_out^T : (4096 x 2048), 128^2 tiles
  gemm_bt<<<(4096 / 128) * (2048 / 128), 512, 0, stream>>>(attnb, woutb,
                                                           out_attn, 4096,
                                                           2048, 2048);
}